// Round 7
// baseline (41.985 us; speedup 1.0000x reference)
//
#include <hip/hip_runtime.h>
#include <hip/hip_bf16.h>

// Problem constants (fixed by setup_inputs):
//   x: (64, 8192) f32   weight: (8192, 2048) f32
//   random_numbers: (4,) int (int32 or int64 storage, values in [1, 2^20))
//   y: (64, 8192) f32
#define K_FULL   8192
#define M_ROWS   64
#define N_OUT    8192
#define N_COMP   2048
#define P_MERS   2147483647

// ws layout: [0, 256KB) : xcB bf16 [M_ROWS][N_COMP]

typedef __attribute__((ext_vector_type(8))) short bf16x8;
typedef __attribute__((ext_vector_type(4))) short s16x4;
typedef __attribute__((ext_vector_type(4))) float f32x4;

__device__ __forceinline__ short f2bfs(float f) {
    __hip_bfloat16 h = __float2bfloat16(f);
    return *reinterpret_cast<short*>(&h);
}

__device__ __forceinline__ int hash_col(int j, int rn0, int rn1, int rn2, int rn3) {
    if (rn1 == 0 && rn3 == 0) {
        // int64 storage (JAX x64 on): exact hash; x = r0*j + r2 < 2^53.
        // Mersenne fold: 2^31 === 1 (mod P)
        unsigned long long xx = (unsigned long long)(unsigned int)rn0 * (unsigned int)j
                              + (unsigned long long)(unsigned int)rn2;
        unsigned long long t = (xx & (unsigned long long)P_MERS) + (xx >> 31);
        if (t >= (unsigned long long)P_MERS) t -= (unsigned long long)P_MERS;
        return (int)(t & (N_COMP - 1));
    } else {
        // int32 storage (JAX x64 off): int32 wraparound + floored mod
        unsigned int t = (unsigned int)rn0 * (unsigned int)j + (unsigned int)rn1;
        int ti = (int)t;
        int m1 = ti % P_MERS;
        if (m1 < 0) m1 += P_MERS;
        return m1 & (N_COMP - 1);
    }
}

// Fused: build compressed row xc[m][*] in LDS (scatter-add), pack to bf16
// xcB[m][*], and zero y[m][*] (required: gemm accumulates with atomics and
// the harness does not re-zero d_out between graph replays).
__global__ __launch_bounds__(1024) void k_xc(const float* __restrict__ x,
                                             const int* __restrict__ rn,
                                             unsigned short* __restrict__ xcB,
                                             float* __restrict__ y) {
    __shared__ float row[N_COMP];
    const int m = blockIdx.x;
    const int tid = threadIdx.x;
    row[tid] = 0.0f;
    row[tid + 1024] = 0.0f;
    // zero y row m (8192 f32 = 1024 thr x 2 float4)
    float4 z = {0.f, 0.f, 0.f, 0.f};
    *(float4*)(y + (size_t)m * N_OUT + tid * 4) = z;
    *(float4*)(y + (size_t)m * N_OUT + 4096 + tid * 4) = z;
    const int rn0 = rn[0], rn1 = rn[1], rn2 = rn[2], rn3 = rn[3];
    __syncthreads();

    const float* xm = x + (size_t)m * K_FULL;
#pragma unroll
    for (int it = 0; it < 2; ++it) {
        int j0 = tid * 4 + it * 4096;
        float4 v = *(const float4*)(xm + j0);
        atomicAdd(&row[hash_col(j0 + 0, rn0, rn1, rn2, rn3)], v.x);
        atomicAdd(&row[hash_col(j0 + 1, rn0, rn1, rn2, rn3)], v.y);
        atomicAdd(&row[hash_col(j0 + 2, rn0, rn1, rn2, rn3)], v.z);
        atomicAdd(&row[hash_col(j0 + 3, rn0, rn1, rn2, rn3)], v.w);
    }
    __syncthreads();

    unsigned int pk = (unsigned int)(unsigned short)f2bfs(row[2 * tid])
                    | ((unsigned int)(unsigned short)f2bfs(row[2 * tid + 1]) << 16);
    ((unsigned int*)(xcB + (size_t)m * N_COMP))[tid] = pk;
}

// MFMA GEMM v3: y[m][n] += sum_{c in kslice} xc[m][c] * W[n][c]
// Grid: 512 n-tiles x 4 k-slices = 2048 blocks x 256 thr (4 waves).
// Stage W panel (16 rows x 512 k) through LDS with 1KB-contiguous wave
// streams (one row per load instruction), bf16-converted. Waves split the
// 512-k slice 4-way, LDS-reduce, then atomicAdd f32 partials into y.
#define NT      16
#define KS      4
#define KSLB    (N_COMP / KS)    // 512
#define WROW_S  522              // padded row stride (shorts); 261 dwords -> bank-spread

__global__ __launch_bounds__(256, 4) void k_gemm(const float* __restrict__ W,
                                                 const unsigned short* __restrict__ xcB,
                                                 float* __restrict__ y) {
    __shared__ unsigned short wt[NT * WROW_S];   // ~16.7 KB
    __shared__ float ys[KS][M_ROWS][NT];         // 16 KB
    const int tid  = threadIdx.x;
    const int lane = tid & 63;
    const int w    = __builtin_amdgcn_readfirstlane(tid >> 6);
    const int nr   = lane & 15;
    const int kg   = lane >> 4;
    const int n0   = (blockIdx.x >> 2) * NT;
    const int kb   = (blockIdx.x & 3) * KSLB;

    // ---- stage: wave w loads rows 4w..4w+3; per row two 1KB-contiguous loads
#pragma unroll
    for (int i = 0; i < 4; ++i) {
        int r = w * 4 + i;
        const float* wr = W + (size_t)(n0 + r) * N_COMP + kb;
        float4 va = *(const float4*)(wr + lane * 4);          // k [0,256)
        float4 vb = *(const float4*)(wr + 256 + lane * 4);    // k [256,512)
        s16x4 pa = { f2bfs(va.x), f2bfs(va.y), f2bfs(va.z), f2bfs(va.w) };
        s16x4 pb = { f2bfs(vb.x), f2bfs(vb.y), f2bfs(vb.z), f2bfs(vb.w) };
        *(s16x4*)&wt[r * WROW_S + lane * 4]       = pa;       // ds_write_b64
        *(s16x4*)&wt[r * WROW_S + 256 + lane * 4] = pb;
    }
    __syncthreads();

    // ---- compute: wave w covers k-sub [kb + w*128, +128)
    f32x4 acc0 = {0.f, 0.f, 0.f, 0.f};
    f32x4 acc1 = {0.f, 0.f, 0.f, 0.f};
    f32x4 acc2 = {0.f, 0.f, 0.f, 0.f};
    f32x4 acc3 = {0.f, 0.f, 0.f, 0.f};
    const unsigned short* ap = xcB + (size_t)nr * N_COMP + kb + w * 128 + kg * 8;
    const unsigned short* bp = wt + nr * WROW_S + w * 128 + kg * 8;

#pragma unroll
    for (int s = 0; s < 4; ++s) {
        const int ko = s * 32;
        bf16x8 b  = *(const bf16x8*)(bp + ko);                    // ds_read_b128
        bf16x8 a0 = *(const bf16x8*)(ap + ko);
        bf16x8 a1 = *(const bf16x8*)(ap + 16 * N_COMP + ko);
        bf16x8 a2 = *(const bf16x8*)(ap + 32 * N_COMP + ko);
        bf16x8 a3 = *(const bf16x8*)(ap + 48 * N_COMP + ko);
        acc0 = __builtin_amdgcn_mfma_f32_16x16x32_bf16(a0, b, acc0, 0, 0, 0);
        acc1 = __builtin_amdgcn_mfma_f32_16x16x32_bf16(a1, b, acc1, 0, 0, 0);
        acc2 = __builtin_amdgcn_mfma_f32_16x16x32_bf16(a2, b, acc2, 0, 0, 0);
        acc3 = __builtin_amdgcn_mfma_f32_16x16x32_bf16(a3, b, acc3, 0, 0, 0);
    }

    // C/D layout (m89-verified): col = lane&15, row = (lane>>4)*4 + j
#pragma unroll
    for (int j = 0; j < 4; ++j) {
        ys[w][ 0 + kg * 4 + j][nr] = acc0[j];
        ys[w][16 + kg * 4 + j][nr] = acc1[j];
        ys[w][32 + kg * 4 + j][nr] = acc2[j];
        ys[w][48 + kg * 4 + j][nr] = acc3[j];
    }
    __syncthreads();

    // reduce 4 waves, accumulate k-slice partial into y (f32 atomics)
#pragma unroll
    for (int i = 0; i < 4; ++i) {
        int o = tid + 256 * i;
        int m = o >> 4;
        int n = o & 15;
        float s = ys[0][m][n] + ys[1][m][n] + ys[2][m][n] + ys[3][m][n];
        atomicAdd(&y[(size_t)m * N_OUT + n0 + n], s);
    }
}

extern "C" void kernel_launch(void* const* d_in, const int* in_sizes, int n_in,
                              void* d_out, int out_size, void* d_ws, size_t ws_size,
                              hipStream_t stream) {
    const float* x = (const float*)d_in[0];
    const float* W = (const float*)d_in[1];
    const int* rn  = (const int*)d_in[2];
    float* y       = (float*)d_out;

    unsigned short* xcB = (unsigned short*)d_ws;

    k_xc<<<M_ROWS, 1024, 0, stream>>>(x, rn, xcB, y);
    k_gemm<<<(N_OUT / NT) * KS, 256, 0, stream>>>(W, xcB, y);
}

// Round 8
// 32.097 us; speedup vs baseline: 1.3080x; 1.3080x over previous
//
#include <hip/hip_runtime.h>
#include <hip/hip_bf16.h>

// Problem constants (fixed by setup_inputs):
//   x: (64, 8192) f32   weight: (8192, 2048) f32
//   random_numbers: (4,) int (int32 or int64 storage, values in [1, 2^20))
//   y: (64, 8192) f32
#define K_FULL   8192
#define M_ROWS   64
#define N_OUT    8192
#define N_COMP   2048
#define P_MERS   2147483647

// ws layout: [0, 256KB) : xcF bf16, fragment-major:
//   xcF[((s*4 + g)*64 + lane)*8 + e] = xc[g*16 + (lane&15)][s*32 + (lane>>4)*8 + e]
//   (s = k-step 0..63, g = m-group 0..3) -> every A-fragment load is 64x16B contiguous.

typedef __attribute__((ext_vector_type(8))) short bf16x8;
typedef __attribute__((ext_vector_type(4))) float f32x4;

__device__ __forceinline__ short f2bfs(float f) {
    __hip_bfloat16 h = __float2bfloat16(f);
    return *reinterpret_cast<short*>(&h);
}

__device__ __forceinline__ int hash_col(int j, int rn0, int rn1, int rn2, int rn3) {
    if (rn1 == 0 && rn3 == 0) {
        // int64 storage (JAX x64 on): exact hash; Mersenne fold (2^31 === 1 mod P)
        unsigned long long xx = (unsigned long long)(unsigned int)rn0 * (unsigned int)j
                              + (unsigned long long)(unsigned int)rn2;
        unsigned long long t = (xx & (unsigned long long)P_MERS) + (xx >> 31);
        if (t >= (unsigned long long)P_MERS) t -= (unsigned long long)P_MERS;
        return (int)(t & (N_COMP - 1));
    } else {
        // int32 storage (JAX x64 off): int32 wraparound + floored mod
        unsigned int t = (unsigned int)rn0 * (unsigned int)j + (unsigned int)rn1;
        int ti = (int)t;
        int m1 = ti % P_MERS;
        if (m1 < 0) m1 += P_MERS;
        return m1 & (N_COMP - 1);
    }
}

// Fused scatter+pack: block = one m row. LDS scatter-add, then pack bf16 into
// fragment-major xcF (scattered dword writes, 4KB/block -> negligible).
__global__ __launch_bounds__(1024) void k_xc(const float* __restrict__ x,
                                             const int* __restrict__ rn,
                                             unsigned int* __restrict__ xcF) {
    __shared__ float row[N_COMP];
    const int m = blockIdx.x;
    const int tid = threadIdx.x;
    row[tid] = 0.0f;
    row[tid + 1024] = 0.0f;
    const int rn0 = rn[0], rn1 = rn[1], rn2 = rn[2], rn3 = rn[3];
    __syncthreads();

    const float* xm = x + (size_t)m * K_FULL;
#pragma unroll
    for (int it = 0; it < 2; ++it) {
        int j0 = tid * 4 + it * 4096;
        float4 v = *(const float4*)(xm + j0);
        atomicAdd(&row[hash_col(j0 + 0, rn0, rn1, rn2, rn3)], v.x);
        atomicAdd(&row[hash_col(j0 + 1, rn0, rn1, rn2, rn3)], v.y);
        atomicAdd(&row[hash_col(j0 + 2, rn0, rn1, rn2, rn3)], v.z);
        atomicAdd(&row[hash_col(j0 + 3, rn0, rn1, rn2, rn3)], v.w);
    }
    __syncthreads();

    // pack c0=2*tid, c0+1 (same s,kg; adjacent e -> one dword)
    const int c0 = 2 * tid;
    const int s  = c0 >> 5;
    const int kg = (c0 >> 3) & 3;
    const int e0 = c0 & 7;
    const int g  = m >> 4;
    const int nr = m & 15;
    unsigned int pk = (unsigned int)(unsigned short)f2bfs(row[c0])
                    | ((unsigned int)(unsigned short)f2bfs(row[c0 + 1]) << 16);
    xcF[(((s * 4 + g) * 64 + kg * 16 + nr) << 2) + (e0 >> 1)] = pk;
}

// MFMA GEMM v4: block = 16 n-cols x all 2048 k, 512 thr (8 waves).
// 8 phases x 256 k. Per phase: stage W[16][256] f32->bf16 into LDS (contiguous
// 1KB wave-loads, double-buffered), then wave w computes k-step s = p*8 + w
// (4 MFMAs, A direct from fragment-major xcF, contiguous). LDS reduce of the
// 8 k-slices at the end; direct coalesced stores (no atomics).
#define WROWD 132   // LDS W-tile row stride in dwords (16B-aligned, bank-spread)

__global__ __launch_bounds__(512) void k_gemm(const float* __restrict__ W,
                                              const unsigned short* __restrict__ xcF,
                                              float* __restrict__ y) {
    __shared__ unsigned int wt[2][16 * WROWD];   // 2 x 8.25 KB
    __shared__ float ys[8][M_ROWS][16];          // 32 KB
    const int tid  = threadIdx.x;
    const int lane = tid & 63;
    const int w    = __builtin_amdgcn_readfirstlane(tid >> 6);  // wave 0..7
    const int nr   = lane & 15;
    const int kg   = lane >> 4;
    const int n0   = blockIdx.x * 16;
    const int r0   = 2 * w;                      // rows staged by this wave

    const float* wrow = W + (size_t)(n0 + r0) * N_COMP;   // + p*256 + lane*4
    // A pointer for phase p: xcF16 + (((p*8+w)*4+g)*64 + lane)*8 shorts
    const unsigned short* ab = xcF + (size_t)((w * 4) * 64 + lane) * 8;

    f32x4 acc0 = {0.f, 0.f, 0.f, 0.f};
    f32x4 acc1 = {0.f, 0.f, 0.f, 0.f};
    f32x4 acc2 = {0.f, 0.f, 0.f, 0.f};
    f32x4 acc3 = {0.f, 0.f, 0.f, 0.f};

    // ---- prologue: stage phase 0
    float4 va = *(const float4*)(wrow + lane * 4);
    float4 vb = *(const float4*)(wrow + N_COMP + lane * 4);
    {
        uint2 pa = { (unsigned int)(unsigned short)f2bfs(va.x) |
                     ((unsigned int)(unsigned short)f2bfs(va.y) << 16),
                     (unsigned int)(unsigned short)f2bfs(va.z) |
                     ((unsigned int)(unsigned short)f2bfs(va.w) << 16) };
        uint2 pb = { (unsigned int)(unsigned short)f2bfs(vb.x) |
                     ((unsigned int)(unsigned short)f2bfs(vb.y) << 16),
                     (unsigned int)(unsigned short)f2bfs(vb.z) |
                     ((unsigned int)(unsigned short)f2bfs(vb.w) << 16) };
        *(uint2*)&wt[0][r0 * WROWD + lane * 2]       = pa;
        *(uint2*)&wt[0][(r0 + 1) * WROWD + lane * 2] = pb;
    }
    // prefetch A for phase 0
    bf16x8 a0 = *(const bf16x8*)(ab + 0 * 512);
    bf16x8 a1 = *(const bf16x8*)(ab + 1 * 512);
    bf16x8 a2 = *(const bf16x8*)(ab + 2 * 512);
    bf16x8 a3 = *(const bf16x8*)(ab + 3 * 512);
    __syncthreads();

#pragma unroll 1
    for (int p = 0; p < 8; ++p) {
        const int b = p & 1;
        float4 nva, nvb;
        bf16x8 na0, na1, na2, na3;
        if (p < 7) {
            // issue next-phase global loads early
            nva = *(const float4*)(wrow + (p + 1) * 256 + lane * 4);
            nvb = *(const float4*)(wrow + (p + 1) * 256 + N_COMP + lane * 4);
            const unsigned short* nab = ab + (size_t)(p + 1) * 8 * 4 * 64 * 8;
            na0 = *(const bf16x8*)(nab + 0 * 512);
            na1 = *(const bf16x8*)(nab + 1 * 512);
            na2 = *(const bf16x8*)(nab + 2 * 512);
            na3 = *(const bf16x8*)(nab + 3 * 512);
        }
        // compute phase p: B fragment from LDS tile, k-offset w*64B + kg*16B
        bf16x8 bf = *(const bf16x8*)((const unsigned short*)&wt[b][0]
                                     + nr * (WROWD * 2) + w * 32 + kg * 8);
        acc0 = __builtin_amdgcn_mfma_f32_16x16x32_bf16(a0, bf, acc0, 0, 0, 0);
        acc1 = __builtin_amdgcn_mfma_f32_16x16x32_bf16(a1, bf, acc1, 0, 0, 0);
        acc2 = __builtin_amdgcn_mfma_f32_16x16x32_bf16(a2, bf, acc2, 0, 0, 0);
        acc3 = __builtin_amdgcn_mfma_f32_16x16x32_bf16(a3, bf, acc3, 0, 0, 0);
        if (p < 7) {
            uint2 pa = { (unsigned int)(unsigned short)f2bfs(nva.x) |
                         ((unsigned int)(unsigned short)f2bfs(nva.y) << 16),
                         (unsigned int)(unsigned short)f2bfs(nva.z) |
                         ((unsigned int)(unsigned short)f2bfs(nva.w) << 16) };
            uint2 pb = { (unsigned int)(unsigned short)f2bfs(nvb.x) |
                         ((unsigned int)(unsigned short)f2bfs(nvb.y) << 16),
                         (unsigned int)(unsigned short)f2bfs(nvb.z) |
                         ((unsigned int)(unsigned short)f2bfs(nvb.w) << 16) };
            *(uint2*)&wt[b ^ 1][r0 * WROWD + lane * 2]       = pa;
            *(uint2*)&wt[b ^ 1][(r0 + 1) * WROWD + lane * 2] = pb;
            a0 = na0; a1 = na1; a2 = na2; a3 = na3;
        }
        __syncthreads();
    }

    // C/D layout (m89-verified): col = lane&15, row = (lane>>4)*4 + j
#pragma unroll
    for (int j = 0; j < 4; ++j) {
        ys[w][ 0 + kg * 4 + j][nr] = acc0[j];
        ys[w][16 + kg * 4 + j][nr] = acc1[j];
        ys[w][32 + kg * 4 + j][nr] = acc2[j];
        ys[w][48 + kg * 4 + j][nr] = acc3[j];
    }
    __syncthreads();

    // reduce 8 k-slices, direct store: 1024 outputs, 2 per thread
#pragma unroll
    for (int i = 0; i < 2; ++i) {
        int o = tid + 512 * i;
        int m = o >> 4;
        int n = o & 15;
        float s = 0.f;
#pragma unroll
        for (int q = 0; q < 8; ++q) s += ys[q][m][n];
        y[(size_t)m * N_OUT + n0 + n] = s;
    }
}

extern "C" void kernel_launch(void* const* d_in, const int* in_sizes, int n_in,
                              void* d_out, int out_size, void* d_ws, size_t ws_size,
                              hipStream_t stream) {
    const float* x = (const float*)d_in[0];
    const float* W = (const float*)d_in[1];
    const int* rn  = (const int*)d_in[2];
    float* y       = (float*)d_out;

    unsigned int* xcF = (unsigned int*)d_ws;

    k_xc<<<M_ROWS, 1024, 0, stream>>>(x, rn, xcF);
    k_gemm<<<N_OUT / 16, 512, 0, stream>>>(W, (const unsigned short*)xcF, y);
}